// Round 1
// baseline (425.095 us; speedup 1.0000x reference)
//
#include <hip/hip_runtime.h>
#include <stdint.h>

typedef unsigned short u16;
typedef __bf16 bf16_t;
typedef bf16_t bf16x8 __attribute__((ext_vector_type(8)));
typedef float f32x4 __attribute__((ext_vector_type(4)));

__device__ __forceinline__ u16 f2bf(float f) {
  union { float f; unsigned int u; } v; v.f = f;
  return (u16)((v.u + 0x7FFFu + ((v.u >> 16) & 1u)) >> 16);
}

#define MFMA16(a, b, c) __builtin_amdgcn_mfma_f32_16x16x32_bf16((a), (b), (c), 0, 0, 0)
#define GLL16(g, l) __builtin_amdgcn_global_load_lds( \
    (const __attribute__((address_space(1))) void*)(g), \
    (__attribute__((address_space(3))) void*)(l), 16, 0, 0)

#define SCALE 0.07216878364870323f  // 1/sqrt(3*64)

// ---------------- fp32 -> bf16 elementwise ----------------
__global__ void cvt_bf16(const float* __restrict__ in, u16* __restrict__ out, int n4) {
  int i = blockIdx.x * 256 + threadIdx.x;
  if (i >= n4) return;
  float4 v = ((const float4*)in)[i];
  ushort4 o;
  o.x = f2bf(v.x); o.y = f2bf(v.y); o.z = f2bf(v.z); o.w = f2bf(v.w);
  ((ushort4*)out)[i] = o;
}

// ---------------- 1024x1024 fp32 -> bf16 transpose (out[n][k] = in[k][n]) ----------------
__global__ void transp_bf16(const float* __restrict__ in, u16* __restrict__ out) {
  __shared__ float t[32][33];
  int tx = threadIdx.x & 31, ty = threadIdx.x >> 5;
  int x0 = blockIdx.x * 32, y0 = blockIdx.y * 32;
  #pragma unroll
  for (int i = ty; i < 32; i += 8)
    t[i][tx] = in[(size_t)(y0 + i) * 1024 + x0 + tx];
  __syncthreads();
  #pragma unroll
  for (int i = ty; i < 32; i += 8)
    out[(size_t)(x0 + i) * 1024 + y0 + tx] = f2bf(t[tx][i]);
}

// ---------------- bf16 GEMM: C[M,1024] = A[M,1024] * BT[1024,1024]^T + bias ----------------
// mode 0: out[(b*16+h)][s][d]   (q,k)     mode 1: out[(b*16+h)][d][s]   (v)
// mode 2: out[h][r][d]          (rel projections, M=1025)
__global__ void __launch_bounds__(256) gemm_bt(
    const u16* __restrict__ A, const u16* __restrict__ BT,
    const float* __restrict__ bias, u16* __restrict__ out,
    int M, int mode) {
  __shared__ __align__(16) u16 As[4096];
  __shared__ __align__(16) u16 Bs[4096];
  const int K = 1024;
  const int m0 = blockIdx.x * 128, n0 = blockIdx.y * 128;
  const int w = threadIdx.x >> 6, lane = threadIdx.x & 63;
  const int lj = lane & 15, lg = lane >> 4;
  const int wm = (w >> 1) * 64, wn = (w & 1) * 64;

  f32x4 acc[4][4] = {};

  const int chunk0 = w * 128 + lane;
  const int chunk1 = chunk0 + 64;
  int r0 = chunk0 >> 2, s0 = (chunk0 & 3) * 8;
  int r1 = chunk1 >> 2, s1 = (chunk1 & 3) * 8;
  int ar0 = m0 + r0; if (ar0 >= M) ar0 = M - 1;
  int ar1 = m0 + r1; if (ar1 >= M) ar1 = M - 1;
  const u16* ga0 = A + (size_t)ar0 * K + s0;
  const u16* ga1 = A + (size_t)ar1 * K + s1;
  const u16* gb0 = BT + (size_t)(n0 + r0) * K + s0;
  const u16* gb1 = BT + (size_t)(n0 + r1) * K + s1;
  u16* lA0 = As + (w * 2 + 0) * 512;
  u16* lA1 = As + (w * 2 + 1) * 512;
  u16* lB0 = Bs + (w * 2 + 0) * 512;
  u16* lB1 = Bs + (w * 2 + 1) * 512;

  for (int k0 = 0; k0 < K; k0 += 32) {
    GLL16(ga0 + k0, lA0);
    GLL16(ga1 + k0, lA1);
    GLL16(gb0 + k0, lB0);
    GLL16(gb1 + k0, lB1);
    __syncthreads();
    bf16x8 af[4], bf8[4];
    #pragma unroll
    for (int mf = 0; mf < 4; ++mf)
      af[mf] = *(const bf16x8*)(As + (wm + mf * 16 + lj) * 32 + lg * 8);
    #pragma unroll
    for (int nf = 0; nf < 4; ++nf)
      bf8[nf] = *(const bf16x8*)(Bs + (wn + nf * 16 + lj) * 32 + lg * 8);
    #pragma unroll
    for (int mf = 0; mf < 4; ++mf)
      #pragma unroll
      for (int nf = 0; nf < 4; ++nf)
        acc[mf][nf] = MFMA16(af[mf], bf8[nf], acc[mf][nf]);
    __syncthreads();
  }

  #pragma unroll
  for (int mf = 0; mf < 4; ++mf) {
    #pragma unroll
    for (int nf = 0; nf < 4; ++nf) {
      const int j = n0 + wn + nf * 16 + lj;
      const float bj = bias[j];
      #pragma unroll
      for (int r = 0; r < 4; ++r) {
        const int i = m0 + wm + mf * 16 + lg * 4 + r;
        if (i >= M) continue;
        const u16 val = f2bf(acc[mf][nf][r] + bj);
        if (mode == 0) {
          out[(size_t)(((i >> 10) << 4) + (j >> 6)) * 65536 + (size_t)(i & 1023) * 64 + (j & 63)] = val;
        } else if (mode == 1) {
          out[(size_t)(((i >> 10) << 4) + (j >> 6)) * 65536 + (size_t)(j & 63) * 1024 + (i & 1023)] = val;
        } else {
          out[(size_t)(j >> 6) * 65600 + (size_t)i * 64 + (j & 63)] = val;
        }
      }
    }
  }
}

// ---------------- fused disentangled attention ----------------
// grid: 1024 blocks = (b*16+n)*16 + i_tile ; block: 256 threads (4 waves)
// scores[i,j] = (q_i.k_j + q_i.relk[clip(i-j)+512] + k_j.relq[clip(j-i)+512]) * SCALE + mask[b,j]
__global__ void __launch_bounds__(256) attn_fused(
    const u16* __restrict__ qg, const u16* __restrict__ kg, const u16* __restrict__ vtg,
    const u16* __restrict__ rkg, const u16* __restrict__ rqg,
    const float* __restrict__ mask, float* __restrict__ out) {
  __shared__ __align__(16) u16 Qs[64][72];
  __shared__ __align__(16) u16 Ks[64][72];
  __shared__ __align__(16) u16 VTs[64][72];
  __shared__ __align__(16) u16 RKs[128][72];
  __shared__ __align__(16) u16 RQs[128][72];
  __shared__ __align__(16) float Ts[64][128];
  __shared__ __align__(16) float Us[64][128];
  __shared__ __align__(16) u16 Ps[64][72];

  const int bx = blockIdx.x;
  const int it = bx & 15, bn = bx >> 4;
  const int b = bn >> 4, n = bn & 15;
  const int i0 = it * 64;
  const int tid = threadIdx.x, w = tid >> 6, lane = tid & 63;
  const int lj = lane & 15, lg = lane >> 4;

  const u16* qh = qg + (size_t)bn * 65536;
  const u16* kh = kg + (size_t)bn * 65536;
  const u16* vth = vtg + (size_t)bn * 65536;
  const u16* rkh = rkg + (size_t)n * 65600;
  const u16* rqh = rqg + (size_t)n * 65600;
  const float* mk = mask + (size_t)b * 1024;

  // stage Q tile once
  {
    int r = tid >> 2, c = (tid & 3) * 16;
    *(uint4*)(&Qs[r][c])     = *(const uint4*)(qh + (size_t)(i0 + r) * 64 + c);
    *(uint4*)(&Qs[r][c + 8]) = *(const uint4*)(qh + (size_t)(i0 + r) * 64 + c + 8);
  }

  float m_r[4], l_r[4];
  f32x4 accO[4] = {};
  #pragma unroll
  for (int r = 0; r < 4; ++r) { m_r[r] = -3e38f; l_r[r] = 0.f; }

  for (int jt = 0; jt < 16; ++jt) {
    const int j0 = jt * 64;
    __syncthreads();  // previous iteration done reading all LDS tiles
    {
      int r = tid >> 2, c = (tid & 3) * 16;
      *(uint4*)(&Ks[r][c])      = *(const uint4*)(kh + (size_t)(j0 + r) * 64 + c);
      *(uint4*)(&Ks[r][c + 8])  = *(const uint4*)(kh + (size_t)(j0 + r) * 64 + c + 8);
      *(uint4*)(&VTs[r][c])     = *(const uint4*)(vth + (size_t)r * 1024 + j0 + c);
      *(uint4*)(&VTs[r][c + 8]) = *(const uint4*)(vth + (size_t)r * 1024 + j0 + c + 8);
    }
    const int dd = i0 - j0 + 512;
    int w0 = dd - 63; w0 = w0 < 0 ? 0 : (w0 > 897 ? 897 : w0);
    const int ddq = j0 - i0 + 512;
    int w0q = ddq - 63; w0q = w0q < 0 ? 0 : (w0q > 897 ? 897 : w0q);
    {
      int r = tid >> 1, c = (tid & 1) * 32;
      const u16* srk = rkh + (size_t)(w0 + r) * 64 + c;
      *(uint4*)(&RKs[r][c])      = *(const uint4*)(srk);
      *(uint4*)(&RKs[r][c + 8])  = *(const uint4*)(srk + 8);
      *(uint4*)(&RKs[r][c + 16]) = *(const uint4*)(srk + 16);
      *(uint4*)(&RKs[r][c + 24]) = *(const uint4*)(srk + 24);
      const u16* srq = rqh + (size_t)(w0q + r) * 64 + c;
      *(uint4*)(&RQs[r][c])      = *(const uint4*)(srq);
      *(uint4*)(&RQs[r][c + 8])  = *(const uint4*)(srq + 8);
      *(uint4*)(&RQs[r][c + 16]) = *(const uint4*)(srq + 16);
      *(uint4*)(&RQs[r][c + 24]) = *(const uint4*)(srq + 24);
    }
    __syncthreads();  // staging visible

    bf16x8 aq[2], ak[2];
    #pragma unroll
    for (int k2 = 0; k2 < 2; ++k2) {
      aq[k2] = *(const bf16x8*)(&Qs[w * 16 + lj][k2 * 32 + lg * 8]);
      ak[k2] = *(const bf16x8*)(&Ks[w * 16 + lj][k2 * 32 + lg * 8]);
    }
    // c2c: rows i in [w*16, w*16+16)
    f32x4 scc[4];
    #pragma unroll
    for (int jf = 0; jf < 4; ++jf) {
      scc[jf] = (f32x4){0.f, 0.f, 0.f, 0.f};
      #pragma unroll
      for (int k2 = 0; k2 < 2; ++k2) {
        bf16x8 bk8 = *(const bf16x8*)(&Ks[jf * 16 + lj][k2 * 32 + lg * 8]);
        scc[jf] = MFMA16(aq[k2], bk8, scc[jf]);
      }
    }
    // T[i,t] = q_i . relk[w0+t]  (own rows);  U[j,t] = k_j . relq[w0q+t] (rows w*16..)
    #pragma unroll
    for (int tf = 0; tf < 8; ++tf) {
      f32x4 t_ = {0.f, 0.f, 0.f, 0.f};
      f32x4 u_ = {0.f, 0.f, 0.f, 0.f};
      #pragma unroll
      for (int k2 = 0; k2 < 2; ++k2) {
        bf16x8 brk = *(const bf16x8*)(&RKs[tf * 16 + lj][k2 * 32 + lg * 8]);
        bf16x8 brq = *(const bf16x8*)(&RQs[tf * 16 + lj][k2 * 32 + lg * 8]);
        t_ = MFMA16(aq[k2], brk, t_);
        u_ = MFMA16(ak[k2], brq, u_);
      }
      #pragma unroll
      for (int r = 0; r < 4; ++r) {
        Ts[w * 16 + lg * 4 + r][tf * 16 + lj] = t_[r];
        Us[w * 16 + lg * 4 + r][tf * 16 + lj] = u_[r];
      }
    }
    __syncthreads();  // T/U visible cross-wave

    // assemble scores + online softmax
    float sc[4][4];
    float rmax[4] = {-3e38f, -3e38f, -3e38f, -3e38f};
    #pragma unroll
    for (int jf = 0; jf < 4; ++jf) {
      const int j_loc = jf * 16 + lj;
      const int j = j0 + j_loc;
      const float mj = mk[j];
      #pragma unroll
      for (int r = 0; r < 4; ++r) {
        const int i_loc = w * 16 + lg * 4 + r;
        const int i = i0 + i_loc;
        int x1 = i - j + 512; x1 = x1 < 0 ? 0 : (x1 > 1024 ? 1024 : x1);
        int x2 = j - i + 512; x2 = x2 < 0 ? 0 : (x2 > 1024 ? 1024 : x2);
        float s = (scc[jf][r] + Ts[i_loc][x1 - w0] + Us[j_loc][x2 - w0q]) * SCALE + mj;
        sc[jf][r] = s;
        rmax[r] = fmaxf(rmax[r], s);
      }
    }
    #pragma unroll
    for (int off = 1; off < 16; off <<= 1)
      #pragma unroll
      for (int r = 0; r < 4; ++r)
        rmax[r] = fmaxf(rmax[r], __shfl_xor(rmax[r], off));
    float pfac[4], rsum[4];
    #pragma unroll
    for (int r = 0; r < 4; ++r) {
      float mnew = fmaxf(m_r[r], rmax[r]);
      pfac[r] = __expf(m_r[r] - mnew);
      m_r[r] = mnew;
      rsum[r] = 0.f;
    }
    #pragma unroll
    for (int jf = 0; jf < 4; ++jf)
      #pragma unroll
      for (int r = 0; r < 4; ++r) {
        float p = __expf(sc[jf][r] - m_r[r]);
        rsum[r] += p;
        Ps[w * 16 + lg * 4 + r][jf * 16 + lj] = f2bf(p);
      }
    #pragma unroll
    for (int off = 1; off < 16; off <<= 1)
      #pragma unroll
      for (int r = 0; r < 4; ++r)
        rsum[r] += __shfl_xor(rsum[r], off);
    #pragma unroll
    for (int r = 0; r < 4; ++r)
      l_r[r] = l_r[r] * pfac[r] + rsum[r];
    #pragma unroll
    for (int d = 0; d < 4; ++d)
      #pragma unroll
      for (int r = 0; r < 4; ++r)
        accO[d][r] *= pfac[r];
    // PV: O[i,d] += P[i,j] * V[j,d]  (P rows own wave, intra-wave LDS dependency)
    #pragma unroll
    for (int jk = 0; jk < 2; ++jk) {
      bf16x8 ap = *(const bf16x8*)(&Ps[w * 16 + lj][jk * 32 + lg * 8]);
      #pragma unroll
      for (int d = 0; d < 4; ++d) {
        bf16x8 bv8 = *(const bf16x8*)(&VTs[d * 16 + lj][jk * 32 + lg * 8]);
        accO[d] = MFMA16(ap, bv8, accO[d]);
      }
    }
  }

  #pragma unroll
  for (int r = 0; r < 4; ++r) {
    const float inv = 1.f / l_r[r];
    const int i = i0 + w * 16 + lg * 4 + r;
    #pragma unroll
    for (int d = 0; d < 4; ++d)
      out[((size_t)b * 1024 + i) * 1024 + n * 64 + d * 16 + lj] = accO[d][r] * inv;
  }
}

extern "C" void kernel_launch(void* const* d_in, const int* in_sizes, int n_in,
                              void* d_out, int out_size, void* d_ws, size_t ws_size,
                              hipStream_t stream) {
  const float* hs   = (const float*)d_in[0];
  const float* mask = (const float*)d_in[1];
  const float* rel  = (const float*)d_in[2];
  const float* Wq   = (const float*)d_in[3];
  const float* bq   = (const float*)d_in[4];
  const float* Wk   = (const float*)d_in[5];
  const float* bk   = (const float*)d_in[6];
  const float* Wv   = (const float*)d_in[7];
  const float* bv   = (const float*)d_in[8];
  const float* Wpk  = (const float*)d_in[9];
  const float* bpk  = (const float*)d_in[10];
  const float* Wpq  = (const float*)d_in[11];
  const float* bpq  = (const float*)d_in[12];
  float* outp = (float*)d_out;

  u16* p = (u16*)d_ws;
  u16* hsb  = p; p += (size_t)4096 * 1024;
  u16* relb = p; p += (size_t)1025 * 1024;
  u16* WqT  = p; p += (size_t)1024 * 1024;
  u16* WkT  = p; p += (size_t)1024 * 1024;
  u16* WvT  = p; p += (size_t)1024 * 1024;
  u16* WpkT = p; p += (size_t)1024 * 1024;
  u16* WpqT = p; p += (size_t)1024 * 1024;
  u16* qws  = p; p += (size_t)4096 * 1024;
  u16* kws  = p; p += (size_t)4096 * 1024;
  u16* vws  = p; p += (size_t)4096 * 1024;
  u16* rkws = p; p += (size_t)16 * 1025 * 64;
  u16* rqws = p; p += (size_t)16 * 1025 * 64;
  if ((size_t)((char*)p - (char*)d_ws) > ws_size) return;  // ws too small: bail

  cvt_bf16<<<4096, 256, 0, stream>>>(hs, hsb, 1048576);
  cvt_bf16<<<1025, 256, 0, stream>>>(rel, relb, 262400);
  transp_bf16<<<dim3(32, 32), 256, 0, stream>>>(Wq,  WqT);
  transp_bf16<<<dim3(32, 32), 256, 0, stream>>>(Wk,  WkT);
  transp_bf16<<<dim3(32, 32), 256, 0, stream>>>(Wv,  WvT);
  transp_bf16<<<dim3(32, 32), 256, 0, stream>>>(Wpk, WpkT);
  transp_bf16<<<dim3(32, 32), 256, 0, stream>>>(Wpq, WpqT);

  gemm_bt<<<dim3(32, 8), 256, 0, stream>>>(hsb, WqT, bq, qws, 4096, 0);
  gemm_bt<<<dim3(32, 8), 256, 0, stream>>>(hsb, WkT, bk, kws, 4096, 0);
  gemm_bt<<<dim3(32, 8), 256, 0, stream>>>(hsb, WvT, bv, vws, 4096, 1);
  gemm_bt<<<dim3(9, 8),  256, 0, stream>>>(relb, WpkT, bpk, rkws, 1025, 2);
  gemm_bt<<<dim3(9, 8),  256, 0, stream>>>(relb, WpqT, bpq, rqws, 1025, 2);

  attn_fused<<<1024, 256, 0, stream>>>(qws, kws, vws, rkws, rqws, mask, outp);
}